// Round 1
// baseline (6313.097 us; speedup 1.0000x reference)
//
#include <hip/hip_runtime.h>
#include <hip/hip_bf16.h>

// ---------------------------------------------------------------------------
// ToyMoE: conv stack (5x conv3x3+bias+relu+maxpool2) -> top-2 gating -> sparse
// expert MLP (fc1+relu, fc2, softmax) -> gate-weighted combine + aux loss.
// Round 1: correctness-first fp32 implementation.
// ---------------------------------------------------------------------------

#define WS_OFF_C1    ((size_t)0)          // 256*128*32*32 = 33,554,432 floats
#define WS_OFF_C2    ((size_t)33554432)   // 256*256*16*16 = 16,777,216
#define WS_OFF_C3    ((size_t)0)          // reuses C1 region (C1 dead by then)
#define WS_OFF_C4    ((size_t)4194304)    // 256*512*4*4   =  2,097,152
#define WS_OFF_FEATS ((size_t)6291456)    // 256*2048      =    524,288
#define WS_OFF_H     ((size_t)6815744)    // 512*4096      =  2,097,152
#define WS_OFF_EO    ((size_t)8912896)    // 512*1024      =    524,288
#define WS_OFF_CTRL  ((size_t)50331648)   // control block (ints+floats)

// ---------------------------------------------------------------------------
// Fused conv3x3(SAME) + bias + relu + maxpool2x2 kernel.
// Block: 64 output channels x (2x2 thread groups), each thread computes a
// PB x PB pooled block (=2PB x 2PB conv pixels). Input tile staged in LDS
// (reads are wave-uniform broadcast -> conflict-free); weights staged with an
// odd LDS stride so the 64-lane co-strided reads hit all 32 banks.
// ---------------------------------------------------------------------------
template<int CI, int CO, int HIN, int WIN, int TP, int PB, int CB>
__global__ __launch_bounds__(256) void conv_pool_kernel(
    const float* __restrict__ in, const float* __restrict__ wgt,
    const float* __restrict__ bias, float* __restrict__ out)
{
    constexpr int PH = HIN / 2, PW = WIN / 2;
    constexpr int IT = 2 * TP + 2;     // LDS input tile edge
    constexpr int CT = 2 * PB;         // conv pixels per thread edge
    constexpr int ST = CT + 2;         // per-thread input support edge
    constexpr int SW = (CB * 9) | 1;   // odd weight stride -> no bank conflicts
    constexpr int NTX = PW / TP;

    __shared__ float lin[CB * IT * IT];
    __shared__ float lw[64 * SW];

    const int tid = threadIdx.x;
    const int co  = tid & 63;
    const int tq  = tid >> 6;          // 0..3 -> 2x2 pixel groups
    const int b   = blockIdx.z;
    const int co0 = blockIdx.y * 64;
    const int ty  = (blockIdx.x / NTX) * TP;
    const int tx  = (blockIdx.x % NTX) * TP;
    const int py0 = ty + (tq >> 1) * PB;
    const int px0 = tx + (tq & 1) * PB;
    const int oy_base = 2 * (py0 - ty);
    const int ox_base = 2 * (px0 - tx);

    float acc[CT][CT];
    #pragma unroll
    for (int i = 0; i < CT; ++i)
        #pragma unroll
        for (int j = 0; j < CT; ++j) acc[i][j] = 0.f;

    for (int ci0 = 0; ci0 < CI; ci0 += CB) {
        __syncthreads();
        // stage input tile (zero-padded at borders)
        for (int i = tid; i < CB * IT * IT; i += 256) {
            int ci = i / (IT * IT);
            int r  = i % (IT * IT);
            int iy = r / IT, ix = r % IT;
            int gy = 2 * ty - 1 + iy, gx = 2 * tx - 1 + ix;
            float v = 0.f;
            if (gy >= 0 && gy < HIN && gx >= 0 && gx < WIN)
                v = in[(((size_t)b * CI + ci0 + ci) * HIN + gy) * WIN + gx];
            lin[i] = v;
        }
        // stage weights for this ci chunk
        for (int i = tid; i < 64 * CB * 9; i += 256) {
            int c = i / (CB * 9);
            int r = i % (CB * 9);
            lw[c * SW + r] = wgt[(((size_t)(co0 + c)) * CI + ci0) * 9 + r];
        }
        __syncthreads();

        #pragma unroll 1
        for (int ci = 0; ci < CB; ++ci) {
            float wr[9];
            #pragma unroll
            for (int k = 0; k < 9; ++k) wr[k] = lw[co * SW + ci * 9 + k];
            const float* base = &lin[ci * IT * IT];
            #pragma unroll
            for (int iy = 0; iy < ST; ++iy) {
                float row[ST];
                #pragma unroll
                for (int j = 0; j < ST; ++j)
                    row[j] = base[(oy_base + iy) * IT + ox_base + j];
                #pragma unroll
                for (int ky = 0; ky < 3; ++ky) {
                    const int oy = iy - ky;
                    if (oy >= 0 && oy < CT) {
                        #pragma unroll
                        for (int kx = 0; kx < 3; ++kx)
                            #pragma unroll
                            for (int ox = 0; ox < CT; ++ox)
                                acc[oy][ox] = fmaf(wr[ky * 3 + kx], row[ox + kx], acc[oy][ox]);
                    }
                }
            }
        }
    }

    const float bv = bias[co0 + co];
    #pragma unroll
    for (int py = 0; py < PB; ++py)
        #pragma unroll
        for (int px = 0; px < PB; ++px) {
            float m = fmaxf(fmaxf(acc[2*py][2*px],   acc[2*py][2*px+1]),
                            fmaxf(acc[2*py+1][2*px], acc[2*py+1][2*px+1]));
            m = fmaxf(m + bv, 0.f);   // relu(max+b) == max(relu(+b)) (monotone)
            out[(((size_t)b * CO + co0 + co) * PH + py0 + py) * PW + px0 + px] = m;
        }
}

// ---------------------------------------------------------------------------
// Gating: one block per token. logits = feats @ w_gate [2048x16], top-2,
// softmax over top-2, atomics for counts / load / importance.
// ---------------------------------------------------------------------------
__global__ __launch_bounds__(256) void gating_kernel(
    const float* __restrict__ feats, const float* __restrict__ wg,
    int* __restrict__ top2idx, float* __restrict__ top2gate,
    int* __restrict__ counts, int* __restrict__ loadcnt,
    float* __restrict__ importance)
{
    __shared__ float red[256 * 17];
    const int b = blockIdx.x, tid = threadIdx.x;
    float acc[16];
    #pragma unroll
    for (int e = 0; e < 16; ++e) acc[e] = 0.f;

    #pragma unroll
    for (int it = 0; it < 8; ++it) {
        int d = tid + it * 256;
        float f = feats[(size_t)b * 2048 + d];
        const float4* w4 = (const float4*)(wg + (size_t)d * 16);
        float4 a = w4[0], c = w4[1], dd = w4[2], g = w4[3];
        acc[0]  = fmaf(f, a.x, acc[0]);  acc[1]  = fmaf(f, a.y, acc[1]);
        acc[2]  = fmaf(f, a.z, acc[2]);  acc[3]  = fmaf(f, a.w, acc[3]);
        acc[4]  = fmaf(f, c.x, acc[4]);  acc[5]  = fmaf(f, c.y, acc[5]);
        acc[6]  = fmaf(f, c.z, acc[6]);  acc[7]  = fmaf(f, c.w, acc[7]);
        acc[8]  = fmaf(f, dd.x, acc[8]); acc[9]  = fmaf(f, dd.y, acc[9]);
        acc[10] = fmaf(f, dd.z, acc[10]);acc[11] = fmaf(f, dd.w, acc[11]);
        acc[12] = fmaf(f, g.x, acc[12]); acc[13] = fmaf(f, g.y, acc[13]);
        acc[14] = fmaf(f, g.z, acc[14]); acc[15] = fmaf(f, g.w, acc[15]);
    }
    #pragma unroll
    for (int e = 0; e < 16; ++e) red[tid * 17 + e] = acc[e];
    __syncthreads();
    for (int s = 128; s >= 1; s >>= 1) {
        if (tid < s) {
            #pragma unroll
            for (int e = 0; e < 16; ++e)
                red[tid * 17 + e] += red[(tid + s) * 17 + e];
        }
        __syncthreads();
    }
    if (tid == 0) {
        float l[16];
        #pragma unroll
        for (int e = 0; e < 16; ++e) l[e] = red[e];
        int i0 = 0;
        for (int e = 1; e < 16; ++e) if (l[e] > l[i0]) i0 = e;
        int i1 = -1;
        for (int e = 0; e < 16; ++e) {
            if (e == i0) continue;
            if (i1 < 0 || l[e] > l[i1]) i1 = e;
        }
        float t  = expf(l[i1] - l[i0]);
        float g0 = 1.f / (1.f + t);
        float g1 = t / (1.f + t);
        top2idx[2 * b]     = i0;
        top2idx[2 * b + 1] = i1;
        top2gate[2 * b]     = g0;
        top2gate[2 * b + 1] = g1;
        atomicAdd(&importance[i0], g0);
        atomicAdd(&importance[i1], g1);
        atomicAdd(&counts[i0], 1);
        atomicAdd(&counts[i1], 1);
        if (g0 > 0.f) atomicAdd(&loadcnt[i0], 1);
        if (g1 > 0.f) atomicAdd(&loadcnt[i1], 1);
    }
}

// ---------------------------------------------------------------------------
// Finalize: exclusive scan of counts -> expert offsets, pack (token,slot) ->
// pair index lists, compute aux = 0.01*(cv2(importance)+cv2(load)).
// ---------------------------------------------------------------------------
__global__ __launch_bounds__(512) void finalize_kernel(
    const int* __restrict__ counts, const int* __restrict__ loadcnt,
    const float* __restrict__ importance, const int* __restrict__ top2idx,
    int* __restrict__ goff, int* __restrict__ pair_token,
    int* __restrict__ pair_of_token, float* __restrict__ out_aux)
{
    __shared__ int s_off[17];
    __shared__ int s_cur[16];
    const int tid = threadIdx.x;
    if (tid < 16) s_cur[tid] = 0;
    if (tid == 0) {
        int o = 0;
        for (int e = 0; e < 16; ++e) { s_off[e] = o; o += counts[e]; }
        s_off[16] = o;
        float mi = 0.f, ml = 0.f;
        for (int e = 0; e < 16; ++e) { mi += importance[e]; ml += (float)loadcnt[e]; }
        mi *= (1.f / 16.f); ml *= (1.f / 16.f);
        float vi = 0.f, vl = 0.f;
        for (int e = 0; e < 16; ++e) {
            float di = importance[e] - mi; vi += di * di;
            float dl = (float)loadcnt[e] - ml; vl += dl * dl;
        }
        vi *= (1.f / 16.f); vl *= (1.f / 16.f);
        out_aux[0] = 0.01f * (vi / (mi * mi + 1e-10f) + vl / (ml * ml + 1e-10f));
    }
    __syncthreads();
    if (tid < 17) goff[tid] = s_off[tid];
    const int e   = top2idx[tid];        // tid = b*2 + slot
    const int pos = atomicAdd(&s_cur[e], 1);
    const int pair = s_off[e] + pos;
    pair_token[pair]    = tid >> 1;
    pair_of_token[tid]  = pair;
}

// ---------------------------------------------------------------------------
// Per-expert GEMM: Y[pairs, N] = (relu)(X[rows, D] @ W[e] + b[e]).
// Tile: 32 tokens x 128 N-cols per block, K chunked by 32 through LDS.
// GATHER: rows come from pair_token (fc1 reads feats); else rows are pairs (h).
// ---------------------------------------------------------------------------
template<int D, int N, bool RELU, bool GATHER>
__global__ __launch_bounds__(256) void fc_kernel(
    const float* __restrict__ X, const float* __restrict__ W,
    const float* __restrict__ bias, float* __restrict__ Y,
    const int* __restrict__ pair_token, const int* __restrict__ goff,
    const int* __restrict__ counts)
{
    const int e   = blockIdx.z;
    const int n_e = counts[e];
    const int t0  = blockIdx.y * 32;
    if (t0 >= n_e) return;
    const int nb  = blockIdx.x * 128;
    const int off = goff[e];
    const float* We = W + (size_t)e * D * N;
    const float* be = bias + (size_t)e * N;

    __shared__ __align__(16) float Xt[32 * 36];
    __shared__ __align__(16) float Wt[32 * 132];
    __shared__ int rowidx[32];

    const int tid = threadIdx.x;
    const int thr_tok = tid >> 5;   // 0..7 -> 4 tokens each
    const int thr_n   = tid & 31;   // 0..31 -> 4 cols each

    if (tid < 32) {
        int tt = min(t0 + tid, n_e - 1);
        rowidx[tid] = GATHER ? pair_token[off + tt] : (off + tt);
    }
    __syncthreads();

    float acc[4][4];
    #pragma unroll
    for (int i = 0; i < 4; ++i)
        #pragma unroll
        for (int j = 0; j < 4; ++j) acc[i][j] = 0.f;

    for (int d0 = 0; d0 < D; d0 += 32) {
        for (int i = tid; i < 1024; i += 256) {
            int t = i >> 5, dd = i & 31;
            Xt[dd * 36 + t] = X[(size_t)rowidx[t] * D + d0 + dd];
        }
        for (int i = tid; i < 4096; i += 256) {
            int dd = i >> 7, n = i & 127;
            Wt[dd * 132 + n] = We[(size_t)(d0 + dd) * N + nb + n];
        }
        __syncthreads();
        #pragma unroll
        for (int dd = 0; dd < 32; ++dd) {
            float4 xv = *(const float4*)&Xt[dd * 36 + thr_tok * 4];
            float4 wv = *(const float4*)&Wt[dd * 132 + thr_n * 4];
            acc[0][0] = fmaf(xv.x, wv.x, acc[0][0]);
            acc[0][1] = fmaf(xv.x, wv.y, acc[0][1]);
            acc[0][2] = fmaf(xv.x, wv.z, acc[0][2]);
            acc[0][3] = fmaf(xv.x, wv.w, acc[0][3]);
            acc[1][0] = fmaf(xv.y, wv.x, acc[1][0]);
            acc[1][1] = fmaf(xv.y, wv.y, acc[1][1]);
            acc[1][2] = fmaf(xv.y, wv.z, acc[1][2]);
            acc[1][3] = fmaf(xv.y, wv.w, acc[1][3]);
            acc[2][0] = fmaf(xv.z, wv.x, acc[2][0]);
            acc[2][1] = fmaf(xv.z, wv.y, acc[2][1]);
            acc[2][2] = fmaf(xv.z, wv.z, acc[2][2]);
            acc[2][3] = fmaf(xv.z, wv.w, acc[2][3]);
            acc[3][0] = fmaf(xv.w, wv.x, acc[3][0]);
            acc[3][1] = fmaf(xv.w, wv.y, acc[3][1]);
            acc[3][2] = fmaf(xv.w, wv.z, acc[3][2]);
            acc[3][3] = fmaf(xv.w, wv.w, acc[3][3]);
        }
        __syncthreads();
    }

    const float4 bvv = *(const float4*)&be[nb + thr_n * 4];
    #pragma unroll
    for (int i = 0; i < 4; ++i) {
        int t = t0 + thr_tok * 4 + i;
        if (t < n_e) {
            float4 v;
            v.x = acc[i][0] + bvv.x;
            v.y = acc[i][1] + bvv.y;
            v.z = acc[i][2] + bvv.z;
            v.w = acc[i][3] + bvv.w;
            if (RELU) {
                v.x = fmaxf(v.x, 0.f); v.y = fmaxf(v.y, 0.f);
                v.z = fmaxf(v.z, 0.f); v.w = fmaxf(v.w, 0.f);
            }
            *(float4*)&Y[(size_t)(off + t) * N + nb + thr_n * 4] = v;
        }
    }
}

// ---------------------------------------------------------------------------
// Row softmax over 1024 entries (in place), one block per pair.
// ---------------------------------------------------------------------------
__global__ __launch_bounds__(256) void softmax_kernel(float* __restrict__ eo)
{
    const int p = blockIdx.x, tid = threadIdx.x;
    float* x = eo + (size_t)p * 1024;
    float v[4];
    #pragma unroll
    for (int k = 0; k < 4; ++k) v[k] = x[tid + k * 256];
    float m = fmaxf(fmaxf(v[0], v[1]), fmaxf(v[2], v[3]));
    __shared__ float s[256];
    s[tid] = m; __syncthreads();
    for (int st = 128; st >= 1; st >>= 1) {
        if (tid < st) s[tid] = fmaxf(s[tid], s[tid + st]);
        __syncthreads();
    }
    m = s[0]; __syncthreads();
    float ex[4]; float sum = 0.f;
    #pragma unroll
    for (int k = 0; k < 4; ++k) { ex[k] = expf(v[k] - m); sum += ex[k]; }
    s[tid] = sum; __syncthreads();
    for (int st = 128; st >= 1; st >>= 1) {
        if (tid < st) s[tid] += s[tid + st];
        __syncthreads();
    }
    const float inv = 1.f / s[0];
    #pragma unroll
    for (int k = 0; k < 4; ++k) x[tid + k * 256] = ex[k] * inv;
}

// ---------------------------------------------------------------------------
// Combine: y[b,:] = g0*eo[p0,:] + g1*eo[p1,:]
// ---------------------------------------------------------------------------
__global__ __launch_bounds__(256) void combine_kernel(
    const float* __restrict__ eo, const int* __restrict__ pair_of_token,
    const float* __restrict__ top2gate, float* __restrict__ y)
{
    const int b = blockIdx.x, tid = threadIdx.x;
    const int p0 = pair_of_token[2 * b], p1 = pair_of_token[2 * b + 1];
    const float g0 = top2gate[2 * b], g1 = top2gate[2 * b + 1];
    #pragma unroll
    for (int k = 0; k < 4; ++k) {
        int o = tid + k * 256;
        y[(size_t)b * 1024 + o] =
            g0 * eo[(size_t)p0 * 1024 + o] + g1 * eo[(size_t)p1 * 1024 + o];
    }
}

// ---------------------------------------------------------------------------
extern "C" void kernel_launch(void* const* d_in, const int* in_sizes, int n_in,
                              void* d_out, int out_size, void* d_ws, size_t ws_size,
                              hipStream_t stream)
{
    const float* x      = (const float*)d_in[0];
    const float* cw1    = (const float*)d_in[1];
    const float* cb1    = (const float*)d_in[2];
    const float* cw2    = (const float*)d_in[3];
    const float* cb2    = (const float*)d_in[4];
    const float* cw3    = (const float*)d_in[5];
    const float* cb3    = (const float*)d_in[6];
    const float* cw4    = (const float*)d_in[7];
    const float* cb4    = (const float*)d_in[8];
    const float* cw5    = (const float*)d_in[9];
    const float* cb5    = (const float*)d_in[10];
    const float* w1     = (const float*)d_in[11];
    const float* b1     = (const float*)d_in[12];
    const float* w2     = (const float*)d_in[13];
    const float* b2     = (const float*)d_in[14];
    const float* w_gate = (const float*)d_in[15];

    float* wsf   = (float*)d_ws;
    float* c1    = wsf + WS_OFF_C1;
    float* c2    = wsf + WS_OFF_C2;
    float* c3    = wsf + WS_OFF_C3;
    float* c4    = wsf + WS_OFF_C4;
    float* feats = wsf + WS_OFF_FEATS;
    float* h     = wsf + WS_OFF_H;
    float* eo    = wsf + WS_OFF_EO;

    int*   ctrl_i       = (int*)(wsf + WS_OFF_CTRL);
    int*   counts       = ctrl_i;
    int*   loadcnt      = ctrl_i + 16;
    int*   goff         = ctrl_i + 32;
    int*   top2idx      = ctrl_i + 64;
    int*   pair_token   = ctrl_i + 576;
    int*   pair_of      = ctrl_i + 1088;
    float* ctrl_f       = wsf + WS_OFF_CTRL + 2048;
    float* importance   = ctrl_f;
    float* top2gate     = ctrl_f + 16;

    float* y_out   = (float*)d_out;
    float* aux_out = y_out + 256 * 1024;

    // zero the atomic accumulators (ws is poisoned before every launch)
    hipMemsetAsync(counts, 0, 32 * sizeof(int), stream);
    hipMemsetAsync(importance, 0, 16 * sizeof(float), stream);

    // conv stack
    conv_pool_kernel<3,   128, 64, 64, 8, 4, 3><<<dim3(16, 2, 256), 256, 0, stream>>>(x,  cw1, cb1, c1);
    conv_pool_kernel<128, 256, 32, 32, 8, 4, 8><<<dim3(4,  4, 256), 256, 0, stream>>>(c1, cw2, cb2, c2);
    conv_pool_kernel<256, 256, 16, 16, 8, 4, 8><<<dim3(1,  4, 256), 256, 0, stream>>>(c2, cw3, cb3, c3);
    conv_pool_kernel<256, 512, 8,  8,  4, 2, 8><<<dim3(1,  8, 256), 256, 0, stream>>>(c3, cw4, cb4, c4);
    conv_pool_kernel<512, 512, 4,  4,  2, 1, 8><<<dim3(1,  8, 256), 256, 0, stream>>>(c4, cw5, cb5, feats);

    // gating + dispatch + aux
    gating_kernel<<<256, 256, 0, stream>>>(feats, w_gate, top2idx, top2gate,
                                           counts, loadcnt, importance);
    finalize_kernel<<<1, 512, 0, stream>>>(counts, loadcnt, importance, top2idx,
                                           goff, pair_token, pair_of, aux_out);

    // sparse expert MLPs (512 (token,expert) pairs grouped by expert)
    fc_kernel<2048, 4096, true,  true ><<<dim3(32, 8, 16), 256, 0, stream>>>(
        feats, w1, b1, h, pair_token, goff, counts);
    fc_kernel<4096, 1024, false, false><<<dim3(8,  8, 16), 256, 0, stream>>>(
        h, w2, b2, eo, pair_token, goff, counts);

    softmax_kernel<<<512, 256, 0, stream>>>(eo);
    combine_kernel<<<256, 256, 0, stream>>>(eo, pair_of, top2gate, y_out);
}